// Round 2
// baseline (4539.531 us; speedup 1.0000x reference)
//
#include <hip/hip_runtime.h>

#define LSTM_T 2048
#define LSTM_H 64

__device__ __forceinline__ float rl(float v, int lane) {
    return __int_as_float(__builtin_amdgcn_readlane(__float_as_int(v), lane));
}

__device__ __forceinline__ float fast_sigmoid(float x) {
    return 1.0f / (1.0f + __expf(-x));
}

__device__ __forceinline__ float fast_tanh(float x) {
    // tanh(x) = 1 - 2/(exp(2x)+1); saturates correctly at +-inf
    return 1.0f - 2.0f / (__expf(2.0f * x) + 1.0f);
}

// __launch_bounds__(128, 1): min-waves-per-EU = 1 so the allocator may use up
// to 512 VGPRs. Round 1 used (128) alone -> VGPR capped at 80 -> the 128
// resident weight values were NOT register-allocated and were re-loaded every
// timestep. Weights-in-VGPR is the whole point of this layout.
__global__ __launch_bounds__(128, 1) void lstm_cls_kernel(
    const float* __restrict__ x,      // [B, T, 1]
    const float* __restrict__ W_ih,   // [4H, 1]
    const float* __restrict__ W_hh,   // [4H, H]
    const float* __restrict__ b_ih,   // [4H]
    const float* __restrict__ b_hh,   // [4H]
    const float* __restrict__ W_lin,  // [3, H]
    const float* __restrict__ b_lin,  // [3]
    float* __restrict__ out)          // [B, 3]
{
    const int b    = blockIdx.x;
    const int tid  = threadIdx.x;
    const int lane = tid & 63;
    const int wv   = tid >> 6;   // 0: gates i,f   1: gates g,o

    __shared__ float sx[LSTM_T];
    __shared__ float ex[2][4][LSTM_H];   // double-buffered gate exchange

    // ---- stage this batch row of x into LDS (coalesced float4) ----
    {
        const float4* xr  = (const float4*)(x + (size_t)b * LSTM_T);
        float4*       sx4 = (float4*)sx;
        #pragma unroll
        for (int i = 0; i < LSTM_T / 4; i += 128) {
            sx4[i + tid] = xr[i + tid];
        }
    }

    const int rowA = wv * 128 + lane;        // gate block 0 (i) or 2 (g)
    const int rowB = wv * 128 + 64 + lane;   // gate block 1 (f) or 3 (o)

    // ---- recurrent weights: 2 rows per lane, resident in VGPRs ----
    float wA[LSTM_H], wB[LSTM_H];
    {
        const float4* pA = (const float4*)(W_hh + rowA * LSTM_H);
        const float4* pB = (const float4*)(W_hh + rowB * LSTM_H);
        #pragma unroll
        for (int q = 0; q < LSTM_H / 4; ++q) {
            float4 a  = pA[q];
            float4 bb = pB[q];
            wA[4*q+0] = a.x;  wA[4*q+1] = a.y;  wA[4*q+2] = a.z;  wA[4*q+3] = a.w;
            wB[4*q+0] = bb.x; wB[4*q+1] = bb.y; wB[4*q+2] = bb.z; wB[4*q+3] = bb.w;
        }
    }
    const float wihA  = W_ih[rowA];
    const float wihB  = W_ih[rowB];
    const float biasA = b_ih[rowA] + b_hh[rowA];
    const float biasB = b_ih[rowB] + b_hh[rowB];

    float h = 0.0f, c = 0.0f;

    __syncthreads();

    for (int t = 0; t < LSTM_T; ++t) {
        const float xv = sx[t];   // wave-uniform LDS broadcast
        // gates = xp + h @ W_hh^T   (4 accumulator chains for ILP)
        float gA0 = wihA * xv + biasA;
        float gB0 = wihB * xv + biasB;
        float gA1 = 0.0f, gB1 = 0.0f;
        #pragma unroll
        for (int k = 0; k < LSTM_H; k += 2) {
            const float h0 = rl(h, k);
            const float h1 = rl(h, k + 1);
            gA0 += wA[k]     * h0;
            gB0 += wB[k]     * h0;
            gA1 += wA[k + 1] * h1;
            gB1 += wB[k + 1] * h1;
        }
        const float gateA = gA0 + gA1;
        const float gateB = gB0 + gB1;

        float vA, vB;
        if (wv == 0) {                       // wave-uniform branch
            vA = fast_sigmoid(gateA);        // i
            vB = fast_sigmoid(gateB);        // f
        } else {
            vA = fast_tanh(gateA);           // g
            vB = fast_sigmoid(gateB);        // o
        }

        const int p = t & 1;
        ex[p][wv * 2 + 0][lane] = vA;
        ex[p][wv * 2 + 1][lane] = vB;
        __syncthreads();                     // single barrier per step (dbuf)

        float iv, fv, gv, ov;
        if (wv == 0) {
            iv = vA;               fv = vB;
            gv = ex[p][2][lane];   ov = ex[p][3][lane];
        } else {
            iv = ex[p][0][lane];   fv = ex[p][1][lane];
            gv = vA;               ov = vB;
        }
        // both waves update c,h redundantly -> h replicated, no 2nd barrier
        c = fv * c + iv * gv;
        h = ov * fast_tanh(c);
    }

    // ---- final linear [3,H] + log_softmax, wave 0 only ----
    if (wv == 0) {
        float p0 = h * W_lin[0 * LSTM_H + lane];
        float p1 = h * W_lin[1 * LSTM_H + lane];
        float p2 = h * W_lin[2 * LSTM_H + lane];
        #pragma unroll
        for (int off = 32; off > 0; off >>= 1) {
            p0 += __shfl_down(p0, off);
            p1 += __shfl_down(p1, off);
            p2 += __shfl_down(p2, off);
        }
        if (lane == 0) {
            const float l0 = p0 + b_lin[0];
            const float l1 = p1 + b_lin[1];
            const float l2 = p2 + b_lin[2];
            const float m  = fmaxf(l0, fmaxf(l1, l2));
            const float s  = __expf(l0 - m) + __expf(l1 - m) + __expf(l2 - m);
            const float ls = logf(s);
            out[b * 3 + 0] = l0 - m - ls;
            out[b * 3 + 1] = l1 - m - ls;
            out[b * 3 + 2] = l2 - m - ls;
        }
    }
}

extern "C" void kernel_launch(void* const* d_in, const int* in_sizes, int n_in,
                              void* d_out, int out_size, void* d_ws, size_t ws_size,
                              hipStream_t stream) {
    const float* x     = (const float*)d_in[0];
    const float* W_ih  = (const float*)d_in[1];
    const float* W_hh  = (const float*)d_in[2];
    const float* b_ih  = (const float*)d_in[3];
    const float* b_hh  = (const float*)d_in[4];
    const float* W_lin = (const float*)d_in[5];
    const float* b_lin = (const float*)d_in[6];
    float* out = (float*)d_out;

    const int B = in_sizes[0] / LSTM_T;   // 2048
    lstm_cls_kernel<<<B, 128, 0, stream>>>(x, W_ih, W_hh, b_ih, b_hh,
                                           W_lin, b_lin, out);
}

// Round 3
// 1040.869 us; speedup vs baseline: 4.3613x; 4.3613x over previous
//
#include <hip/hip_runtime.h>
#include <hip/hip_bf16.h>

#define T_LEN 2048
#define HDIM  64
#define BT    8            // batches per block
#define CHUNK 512          // x timesteps staged per LDS chunk
#define XS    (CHUNK + 4)  // x row stride (floats), breaks bank alignment
#define HS    72           // h_lds row stride in bf16 (144 B, 16B-aligned)

typedef __attribute__((ext_vector_type(8))) short bf16x8;
typedef __attribute__((ext_vector_type(4))) float f32x4;

__device__ __forceinline__ float rcp_fast(float x) { return __builtin_amdgcn_rcpf(x); }
__device__ __forceinline__ float sigmoid_f(float x) {
    return rcp_fast(1.0f + __expf(-x));
}
__device__ __forceinline__ float tanh_f(float x) {
    // tanh(x) = 1 - 2/(exp(2x)+1); saturates correctly
    return 1.0f - 2.0f * rcp_fast(__expf(2.0f * x) + 1.0f);
}
// float -> bf16, round-to-nearest-even
__device__ __forceinline__ unsigned short f2bf(float f) {
    unsigned int u = __float_as_uint(f);
    u += 0x7fffu + ((u >> 16) & 1u);
    return (unsigned short)(u >> 16);
}

// One block = 8 batches for all T. 4 waves; wave w owns hidden units
// 16w..16w+15 across all four gates (row-tiles w, w+4, w+8, w+12 of the
// 256x64 W_hh) -> each lane holds i,f,g,o for its 4 hidden units x 1 batch
// (C/D: row = hi*4+reg, col = lane&15, m89-verified) -> local c,h update.
// h goes through a double-buffered bf16 LDS tile in B-fragment order;
// one __syncthreads per timestep.
__global__ __launch_bounds__(256, 1) void lstm_mfma_kernel(
    const float* __restrict__ x,      // [B, T, 1]
    const float* __restrict__ W_ih,   // [4H, 1]
    const float* __restrict__ W_hh,   // [4H, H]
    const float* __restrict__ b_ih,   // [4H]
    const float* __restrict__ b_hh,   // [4H]
    const float* __restrict__ W_lin,  // [3, H]
    const float* __restrict__ b_lin,  // [3]
    float* __restrict__ out)          // [B, 3]
{
    const int tid  = threadIdx.x;
    const int lane = tid & 63;
    const int wv   = tid >> 6;     // wave 0..3
    const int col  = lane & 15;    // batch col (valid < 8; cols 8-15 harmless, bounded)
    const int hi   = lane >> 4;    // k/row subgroup
    const int b0   = blockIdx.x * BT;

    __shared__ float sx[BT][XS];
    __shared__ short hl[2][16][HS];
    __shared__ float red[BT][3];

    for (int i = tid; i < 2 * 16 * HS; i += 256) ((short*)hl)[i] = 0;

    // ---- resident W_hh A-fragments (bf16) + per-row wih/bias ----
    bf16x8 wf[4][2];
    float  wih[4][4], bias[4][4];
    #pragma unroll
    for (int g = 0; g < 4; ++g) {
        const int rowA = 64 * g + 16 * wv + col;   // A-frag row (m = lane&15)
        #pragma unroll
        for (int kc = 0; kc < 2; ++kc) {
            const float* p = W_hh + rowA * HDIM + kc * 32 + hi * 8;
            bf16x8 f;
            #pragma unroll
            for (int j = 0; j < 8; ++j) f[j] = (short)f2bf(p[j]);
            wf[g][kc] = f;
        }
        #pragma unroll
        for (int r = 0; r < 4; ++r) {
            const int row = 64 * g + 16 * wv + hi * 4 + r;  // C/D row mapping
            wih[g][r]  = W_ih[row];
            bias[g][r] = b_ih[row] + b_hh[row];
        }
    }

    float c[4]  = {0.f, 0.f, 0.f, 0.f};
    float hf[4] = {0.f, 0.f, 0.f, 0.f};
    const int xrow = col & 7;

    for (int tc0 = 0; tc0 < T_LEN; tc0 += CHUNK) {
        __syncthreads();   // prior chunk fully consumed (covers hl init too)
        {   // stage x chunk: 8 rows x CHUNK floats, coalesced float4
            const int r  = tid >> 5;
            const int c4 = tid & 31;
            const float4* gp = (const float4*)(x + (size_t)(b0 + r) * T_LEN + tc0 + c4 * 4);
            float4*       sp = (float4*)&sx[r][c4 * 4];
            #pragma unroll
            for (int q = 0; q < 4; ++q) sp[q * 32] = gp[q * 32];
        }
        __syncthreads();

        for (int tt = 0; tt < CHUNK; ++tt) {
            const int t  = tc0 + tt;
            const int rb = t & 1, wb = rb ^ 1;

            const float xv = sx[xrow][tt];
            f32x4 acc[4];
            #pragma unroll
            for (int g = 0; g < 4; ++g)
                #pragma unroll
                for (int r = 0; r < 4; ++r)
                    acc[g][r] = bias[g][r] + wih[g][r] * xv;

            const bf16x8 hb0 = *(const bf16x8*)&hl[rb][col][hi * 8];
            const bf16x8 hb1 = *(const bf16x8*)&hl[rb][col][32 + hi * 8];
            #pragma unroll
            for (int g = 0; g < 4; ++g) {
                acc[g] = __builtin_amdgcn_mfma_f32_16x16x32_bf16(wf[g][0], hb0, acc[g], 0, 0, 0);
                acc[g] = __builtin_amdgcn_mfma_f32_16x16x32_bf16(wf[g][1], hb1, acc[g], 0, 0, 0);
            }

            unsigned short hb16[4];
            #pragma unroll
            for (int r = 0; r < 4; ++r) {
                const float iv = sigmoid_f(acc[0][r]);
                const float fv = sigmoid_f(acc[1][r]);
                const float gv = tanh_f(acc[2][r]);
                const float ov = sigmoid_f(acc[3][r]);
                c[r]  = fv * c[r] + iv * gv;
                hf[r] = ov * tanh_f(c[r]);
                hb16[r] = f2bf(hf[r]);
            }
            uint2 pk;
            pk.x = (unsigned int)hb16[0] | ((unsigned int)hb16[1] << 16);
            pk.y = (unsigned int)hb16[2] | ((unsigned int)hb16[3] << 16);
            *(uint2*)&hl[wb][col][16 * wv + hi * 4] = pk;

            __syncthreads();   // next step reads buffer wb
        }
    }

    // ---- epilogue: logits = W_lin @ h_T + b_lin, then log_softmax ----
    float p0 = 0.f, p1 = 0.f, p2 = 0.f;
    #pragma unroll
    for (int r = 0; r < 4; ++r) {
        const int j = 16 * wv + hi * 4 + r;
        p0 += W_lin[0 * HDIM + j] * hf[r];
        p1 += W_lin[1 * HDIM + j] * hf[r];
        p2 += W_lin[2 * HDIM + j] * hf[r];
    }
    if (tid < BT * 3) ((float*)red)[tid] = 0.f;
    __syncthreads();
    if (col < BT) {
        atomicAdd(&red[col][0], p0);
        atomicAdd(&red[col][1], p1);
        atomicAdd(&red[col][2], p2);
    }
    __syncthreads();
    if (tid < BT) {
        const float l0 = red[tid][0] + b_lin[0];
        const float l1 = red[tid][1] + b_lin[1];
        const float l2 = red[tid][2] + b_lin[2];
        const float m  = fmaxf(l0, fmaxf(l1, l2));
        const float s  = __expf(l0 - m) + __expf(l1 - m) + __expf(l2 - m);
        const float ls = __logf(s);
        out[(b0 + tid) * 3 + 0] = l0 - m - ls;
        out[(b0 + tid) * 3 + 1] = l1 - m - ls;
        out[(b0 + tid) * 3 + 2] = l2 - m - ls;
    }
}

extern "C" void kernel_launch(void* const* d_in, const int* in_sizes, int n_in,
                              void* d_out, int out_size, void* d_ws, size_t ws_size,
                              hipStream_t stream) {
    const float* x     = (const float*)d_in[0];
    const float* W_ih  = (const float*)d_in[1];
    const float* W_hh  = (const float*)d_in[2];
    const float* b_ih  = (const float*)d_in[3];
    const float* b_hh  = (const float*)d_in[4];
    const float* W_lin = (const float*)d_in[5];
    const float* b_lin = (const float*)d_in[6];
    float* out = (float*)d_out;

    const int B = in_sizes[0] / T_LEN;   // 2048
    lstm_mfma_kernel<<<B / BT, 256, 0, stream>>>(x, W_ih, W_hh, b_ih, b_hh,
                                                 W_lin, b_lin, out);
}

// Round 4
// 846.873 us; speedup vs baseline: 5.3603x; 1.2291x over previous
//
#include <hip/hip_runtime.h>
#include <hip/hip_bf16.h>

#define T_LEN 2048
#define HDIM  64
#define BT    8            // batches per block
#define CHUNK 512          // x timesteps staged per LDS chunk
#define XS    (CHUNK + 4)  // x row stride (floats)
#define HS    72           // h_lds row stride in bf16 (144 B, 16B-aligned)

typedef __attribute__((ext_vector_type(8))) short bf16x8;
typedef __attribute__((ext_vector_type(4))) float f32x4;

__device__ __forceinline__ float rcp_fast(float x) { return __builtin_amdgcn_rcpf(x); }
__device__ __forceinline__ float sigmoid_f(float x) {
    return rcp_fast(1.0f + __expf(-x));
}
__device__ __forceinline__ float tanh_f(float x) {
    return 1.0f - 2.0f * rcp_fast(__expf(2.0f * x) + 1.0f);
}
__device__ __forceinline__ unsigned short f2bf(float f) {
    unsigned int u = __float_as_uint(f);
    u += 0x7fffu + ((u >> 16) & 1u);
    return (unsigned short)(u >> 16);
}

// One block = 8 batches for all T. 4 waves; wave w owns hidden units
// 16w..16w+15 across all four gates. B-fragment is read with bq = col&7, so
// MFMA cols 8-15 duplicate cols 0-7. Lane pair (hi,c)/(hi,c+8) thus holds
// identical acc; lanes c<8 service C/D rows hi*4+{0,1}, lanes c>=8 rows
// hi*4+{2,3} -> per-lane nonlinearity work halves with ZERO exchange traffic.
// (C/D: row = hi*4 + reg, col = lane&15, m89-verified.)
__global__ __launch_bounds__(256, 1) void lstm_mfma_kernel(
    const float* __restrict__ x,      // [B, T, 1]
    const float* __restrict__ W_ih,   // [4H, 1]
    const float* __restrict__ W_hh,   // [4H, H]
    const float* __restrict__ b_ih,   // [4H]
    const float* __restrict__ b_hh,   // [4H]
    const float* __restrict__ W_lin,  // [3, H]
    const float* __restrict__ b_lin,  // [3]
    float* __restrict__ out)          // [B, 3]
{
    const int tid    = threadIdx.x;
    const int lane   = tid & 63;
    const int wv     = tid >> 6;       // wave 0..3
    const int col    = lane & 15;
    const int hi     = lane >> 4;      // k/row subgroup
    const int bq     = col & 7;        // batch serviced by this lane
    const int hiSide = col >> 3;       // 0: C/D rows hi*4+{0,1}; 1: rows hi*4+{2,3}
    const int rb0    = hiSide * 2;
    const int b0     = blockIdx.x * BT;

    __shared__ float sx[BT][XS];
    __shared__ short hl[2][BT][HS];    // double-buffered h (bf16) [batch][hidden]
    __shared__ float red[BT][3];

    for (int i = tid; i < 2 * BT * HS; i += 256) ((short*)hl)[i] = 0;

    // ---- resident W_hh A-fragments (bf16) ----
    bf16x8 wf[4][2];
    #pragma unroll
    for (int g = 0; g < 4; ++g) {
        const int rowA = 64 * g + 16 * wv + col;   // A-frag row (m = lane&15)
        #pragma unroll
        for (int kc = 0; kc < 2; ++kc) {
            const float* p = W_hh + rowA * HDIM + kc * 32 + hi * 8;
            bf16x8 f;
            #pragma unroll
            for (int j = 0; j < 8; ++j) f[j] = (short)f2bf(p[j]);
            wf[g][kc] = f;
        }
    }
    // bias/wih only for this lane's 2 owned C/D rows
    float wih2[4][2], bias2[4][2];
    #pragma unroll
    for (int g = 0; g < 4; ++g) {
        #pragma unroll
        for (int r = 0; r < 2; ++r) {
            const int row = 64 * g + 16 * wv + hi * 4 + rb0 + r;
            wih2[g][r]  = W_ih[row];
            bias2[g][r] = b_ih[row] + b_hh[row];
        }
    }

    float cst[2] = {0.f, 0.f};
    float hf2[2] = {0.f, 0.f};

    for (int tc0 = 0; tc0 < T_LEN; tc0 += CHUNK) {
        __syncthreads();   // prior chunk fully consumed (covers hl init too)
        {   // stage x chunk: 8 rows x CHUNK floats, coalesced float4
            const int r  = tid >> 5;
            const int c4 = tid & 31;
            const float4* gp = (const float4*)(x + (size_t)(b0 + r) * T_LEN + tc0 + c4 * 4);
            float4*       sp = (float4*)&sx[r][c4 * 4];
            #pragma unroll
            for (int q = 0; q < 4; ++q) sp[q * 32] = gp[q * 32];
        }
        __syncthreads();

        for (int tt = 0; tt < CHUNK; ++tt) {
            const int rb = tt & 1, wb = rb ^ 1;

            const float xv = sx[bq][tt];
            f32x4 acc[4];
            #pragma unroll
            for (int g = 0; g < 4; ++g) {
                // C-in placed so whichever reg-pair this lane consumes holds
                // its own rows' bias (regs 0,1 and 2,3 both = {t0,t1})
                const float t0 = bias2[g][0] + wih2[g][0] * xv;
                const float t1 = bias2[g][1] + wih2[g][1] * xv;
                acc[g][0] = t0; acc[g][1] = t1; acc[g][2] = t0; acc[g][3] = t1;
            }

            const bf16x8 hb0 = *(const bf16x8*)&hl[rb][bq][hi * 8];
            const bf16x8 hb1 = *(const bf16x8*)&hl[rb][bq][32 + hi * 8];
            #pragma unroll
            for (int g = 0; g < 4; ++g) {
                acc[g] = __builtin_amdgcn_mfma_f32_16x16x32_bf16(wf[g][0], hb0, acc[g], 0, 0, 0);
                acc[g] = __builtin_amdgcn_mfma_f32_16x16x32_bf16(wf[g][1], hb1, acc[g], 0, 0, 0);
            }

            unsigned short hb16[2];
            #pragma unroll
            for (int r = 0; r < 2; ++r) {
                // compile-time indices on both ternary arms (no dynamic vec idx)
                const float gi = hiSide ? acc[0][2 + r] : acc[0][r];
                const float gf = hiSide ? acc[1][2 + r] : acc[1][r];
                const float gg = hiSide ? acc[2][2 + r] : acc[2][r];
                const float go = hiSide ? acc[3][2 + r] : acc[3][r];
                const float iv = sigmoid_f(gi);
                const float fv = sigmoid_f(gf);
                const float gv = tanh_f(gg);
                const float ov = sigmoid_f(go);
                cst[r] = fv * cst[r] + iv * gv;
                hf2[r] = ov * tanh_f(cst[r]);
                hb16[r] = f2bf(hf2[r]);
            }
            const unsigned int pk =
                (unsigned int)hb16[0] | ((unsigned int)hb16[1] << 16);
            *(unsigned int*)&hl[wb][bq][16 * wv + hi * 4 + rb0] = pk;

            __syncthreads();   // next step reads buffer wb
        }
    }

    // ---- epilogue: logits = W_lin @ h_T + b_lin, then log_softmax ----
    const int j0 = 16 * wv + hi * 4 + rb0;
    float p0 = W_lin[0 * HDIM + j0] * hf2[0] + W_lin[0 * HDIM + j0 + 1] * hf2[1];
    float p1 = W_lin[1 * HDIM + j0] * hf2[0] + W_lin[1 * HDIM + j0 + 1] * hf2[1];
    float p2 = W_lin[2 * HDIM + j0] * hf2[0] + W_lin[2 * HDIM + j0 + 1] * hf2[1];

    if (tid < BT * 3) ((float*)red)[tid] = 0.f;
    __syncthreads();
    atomicAdd(&red[bq][0], p0);
    atomicAdd(&red[bq][1], p1);
    atomicAdd(&red[bq][2], p2);
    __syncthreads();
    if (tid < BT) {
        const float l0 = red[tid][0] + b_lin[0];
        const float l1 = red[tid][1] + b_lin[1];
        const float l2 = red[tid][2] + b_lin[2];
        const float m  = fmaxf(l0, fmaxf(l1, l2));
        const float s  = __expf(l0 - m) + __expf(l1 - m) + __expf(l2 - m);
        const float ls = __logf(s);
        out[(b0 + tid) * 3 + 0] = l0 - m - ls;
        out[(b0 + tid) * 3 + 1] = l1 - m - ls;
        out[(b0 + tid) * 3 + 2] = l2 - m - ls;
    }
}

extern "C" void kernel_launch(void* const* d_in, const int* in_sizes, int n_in,
                              void* d_out, int out_size, void* d_ws, size_t ws_size,
                              hipStream_t stream) {
    const float* x     = (const float*)d_in[0];
    const float* W_ih  = (const float*)d_in[1];
    const float* W_hh  = (const float*)d_in[2];
    const float* b_ih  = (const float*)d_in[3];
    const float* b_hh  = (const float*)d_in[4];
    const float* W_lin = (const float*)d_in[5];
    const float* b_lin = (const float*)d_in[6];
    float* out = (float*)d_out;

    const int B = in_sizes[0] / T_LEN;   // 2048
    lstm_mfma_kernel<<<B / BT, 256, 0, stream>>>(x, W_ih, W_hh, b_ih, b_hh,
                                                 W_lin, b_lin, out);
}

// Round 5
// 781.015 us; speedup vs baseline: 5.8123x; 1.0843x over previous
//
#include <hip/hip_runtime.h>
#include <hip/hip_bf16.h>

#define T_LEN 2048
#define HDIM  64
#define BT    4            // batches per block -> 512 blocks = 2 blocks/CU
#define XS    (T_LEN + 4)  // x row stride (floats): pad kills stride-2048 bank alias
#define HS    72           // h_lds row stride in bf16 (144 B, 16B-aligned)

typedef __attribute__((ext_vector_type(8))) short bf16x8;
typedef __attribute__((ext_vector_type(4))) float f32x4;

__device__ __forceinline__ float rcp_fast(float x) { return __builtin_amdgcn_rcpf(x); }
__device__ __forceinline__ float sigmoid_f(float x) {
    return rcp_fast(1.0f + __expf(-x));
}
__device__ __forceinline__ float tanh_f(float x) {
    return 1.0f - 2.0f * rcp_fast(__expf(2.0f * x) + 1.0f);
}
__device__ __forceinline__ unsigned short f2bf(float f) {
    unsigned int u = __float_as_uint(f);
    u += 0x7fffu + ((u >> 16) & 1u);
    return (unsigned short)(u >> 16);
}

// One block = 4 batches for all T; 512 blocks -> 2 co-resident blocks/CU
// (2 waves/SIMD) so independent recurrences hide each other's latency chain.
// 4 waves; wave w owns hidden units 16w..16w+15 across all four gates.
// B-fragment read with bq = col&3 -> MFMA cols duplicate 4x; the 16 cols
// decompose as 4 batches x 4 row-selects s = col>>2. Each lane services
// exactly ONE (hidden row = hi*4+s, batch = col&3) pair: 10 transcendentals
// per lane-step, one ds_write_b16, no cross-lane exchange.
// (C/D: row = hi*4 + reg, col = lane&15, m89-verified.)
__global__ __launch_bounds__(256, 2) void lstm_mfma_kernel(
    const float* __restrict__ x,      // [B, T, 1]
    const float* __restrict__ W_ih,   // [4H, 1]
    const float* __restrict__ W_hh,   // [4H, H]
    const float* __restrict__ b_ih,   // [4H]
    const float* __restrict__ b_hh,   // [4H]
    const float* __restrict__ W_lin,  // [3, H]
    const float* __restrict__ b_lin,  // [3]
    float* __restrict__ out)          // [B, 3]
{
    const int tid  = threadIdx.x;
    const int lane = tid & 63;
    const int wv   = tid >> 6;       // wave 0..3
    const int col  = lane & 15;
    const int hi   = lane >> 4;      // k/row subgroup
    const int bq   = col & 3;        // batch serviced by this lane
    const int s    = col >> 2;       // C/D reg select: row = hi*4 + s
    const int b0   = blockIdx.x * BT;

    __shared__ float sx[BT][XS];        // full x rows for 4 batches (32.8 KB)
    __shared__ short hl[2][BT][HS];     // double-buffered h (bf16)
    __shared__ float red[BT][3];

    for (int i = tid; i < 2 * BT * HS; i += 256) ((short*)hl)[i] = 0;

    // ---- stage all T for the 4 batches (coalesced float4, 8 per thread) ----
    #pragma unroll
    for (int q = 0; q < 8; ++q) {
        const int idx = q * 256 + tid;      // float4 index, 0..2047
        const int row = idx >> 9;           // /512 float4 per batch row
        const int c4  = idx & 511;
        *(float4*)&sx[row][c4 * 4] =
            ((const float4*)(x + (size_t)(b0 + row) * T_LEN))[c4];
    }

    // ---- resident W_hh A-fragments (bf16) ----
    bf16x8 wf[4][2];
    #pragma unroll
    for (int g = 0; g < 4; ++g) {
        const int rowA = 64 * g + 16 * wv + col;   // A-frag row (m = lane&15)
        #pragma unroll
        for (int kc = 0; kc < 2; ++kc) {
            const float* p = W_hh + rowA * HDIM + kc * 32 + hi * 8;
            bf16x8 f;
            #pragma unroll
            for (int j = 0; j < 8; ++j) f[j] = (short)f2bf(p[j]);
            wf[g][kc] = f;
        }
    }
    // bias/wih for this lane's single owned C/D row
    float wih1[4], bias1[4];
    #pragma unroll
    for (int g = 0; g < 4; ++g) {
        const int row = 64 * g + 16 * wv + hi * 4 + s;
        wih1[g]  = W_ih[row];
        bias1[g] = b_ih[row] + b_hh[row];
    }

    float cst = 0.f, hf = 0.f;
    const int sb0 = s & 1, sb1 = s >> 1;
    const int hwr = 16 * wv + hi * 4 + s;   // this lane's hidden index

    __syncthreads();   // covers hl zero-init + sx staging

    for (int t = 0; t < T_LEN; ++t) {
        const int rb = t & 1, wb = rb ^ 1;

        const float xv = sx[bq][t];
        f32x4 acc[4];
        #pragma unroll
        for (int g = 0; g < 4; ++g) {
            // splat this lane's bias into all 4 C regs; only reg s is consumed,
            // so other rows' (wrong-bias) outputs are bounded garbage.
            const float tv = bias1[g] + wih1[g] * xv;
            acc[g][0] = tv; acc[g][1] = tv; acc[g][2] = tv; acc[g][3] = tv;
        }

        const bf16x8 hb0 = *(const bf16x8*)&hl[rb][bq][hi * 8];
        const bf16x8 hb1 = *(const bf16x8*)&hl[rb][bq][32 + hi * 8];
        #pragma unroll
        for (int g = 0; g < 4; ++g) {
            acc[g] = __builtin_amdgcn_mfma_f32_16x16x32_bf16(wf[g][0], hb0, acc[g], 0, 0, 0);
            acc[g] = __builtin_amdgcn_mfma_f32_16x16x32_bf16(wf[g][1], hb1, acc[g], 0, 0, 0);
        }

        // select reg s per gate (compile-time vector indices, vcc cndmask)
        float gsel[4];
        #pragma unroll
        for (int g = 0; g < 4; ++g) {
            const float a01 = sb0 ? acc[g][1] : acc[g][0];
            const float a23 = sb0 ? acc[g][3] : acc[g][2];
            gsel[g] = sb1 ? a23 : a01;
        }

        const float iv = sigmoid_f(gsel[0]);
        const float fv = sigmoid_f(gsel[1]);
        const float gg = tanh_f(gsel[2]);
        const float ov = sigmoid_f(gsel[3]);
        cst = fv * cst + iv * gg;
        hf  = ov * tanh_f(cst);

        hl[wb][bq][hwr] = (short)f2bf(hf);

        __syncthreads();   // next step reads buffer wb
    }

    // ---- epilogue: logits = W_lin @ h_T + b_lin, then log_softmax ----
    float p0 = W_lin[0 * HDIM + hwr] * hf;
    float p1 = W_lin[1 * HDIM + hwr] * hf;
    float p2 = W_lin[2 * HDIM + hwr] * hf;
    // reduce the 16 lanes of each batch group (closed under xor {4,8,16,32})
    #pragma unroll
    for (int m = 4; m <= 32; m <<= 1) {
        p0 += __shfl_xor(p0, m);
        p1 += __shfl_xor(p1, m);
        p2 += __shfl_xor(p2, m);
    }
    if (tid < BT * 3) ((float*)red)[tid] = 0.f;
    __syncthreads();
    if (lane < 4) {   // hi==0, col==lane -> one partial per wave per batch
        atomicAdd(&red[lane][0], p0);
        atomicAdd(&red[lane][1], p1);
        atomicAdd(&red[lane][2], p2);
    }
    __syncthreads();
    if (tid < BT) {
        const float l0 = red[tid][0] + b_lin[0];
        const float l1 = red[tid][1] + b_lin[1];
        const float l2 = red[tid][2] + b_lin[2];
        const float m  = fmaxf(l0, fmaxf(l1, l2));
        const float sm = __expf(l0 - m) + __expf(l1 - m) + __expf(l2 - m);
        const float ls = __logf(sm);
        out[(b0 + tid) * 3 + 0] = l0 - m - ls;
        out[(b0 + tid) * 3 + 1] = l1 - m - ls;
        out[(b0 + tid) * 3 + 2] = l2 - m - ls;
    }
}

extern "C" void kernel_launch(void* const* d_in, const int* in_sizes, int n_in,
                              void* d_out, int out_size, void* d_ws, size_t ws_size,
                              hipStream_t stream) {
    const float* x     = (const float*)d_in[0];
    const float* W_ih  = (const float*)d_in[1];
    const float* W_hh  = (const float*)d_in[2];
    const float* b_ih  = (const float*)d_in[3];
    const float* b_hh  = (const float*)d_in[4];
    const float* W_lin = (const float*)d_in[5];
    const float* b_lin = (const float*)d_in[6];
    float* out = (float*)d_out;

    const int B = in_sizes[0] / T_LEN;   // 2048
    lstm_mfma_kernel<<<B / BT, 256, 0, stream>>>(x, W_ih, W_hh, b_ih, b_hh,
                                                 W_lin, b_lin, out);
}

// Round 6
// 658.577 us; speedup vs baseline: 6.8929x; 1.1859x over previous
//
#include <hip/hip_runtime.h>
#include <hip/hip_bf16.h>

#define T_LEN 2048
#define HDIM  64
#define BT    4            // batches per block -> 512 blocks = 2 blocks/CU
#define XS    (T_LEN + 4)  // x row stride (floats)
#define HS    72           // h_lds row stride in bf16
#define L2E   1.4426950408889634f   // log2(e)
#define L2E2  2.8853900817779268f   // 2*log2(e)

typedef __attribute__((ext_vector_type(8))) short bf16x8;
typedef __attribute__((ext_vector_type(4))) float f32x4;

__device__ __forceinline__ float rcp_f(float x)  { return __builtin_amdgcn_rcpf(x); }
__device__ __forceinline__ float exp2_f(float x) { return __builtin_amdgcn_exp2f(x); }
__device__ __forceinline__ unsigned short f2bf(float f) {
    unsigned int u = __float_as_uint(f);
    u += 0x7fffu + ((u >> 16) & 1u);
    return (unsigned short)(u >> 16);
}

// Round-5 structure (BT=4, 512 blocks, 2/CU; wave w owns 16 hidden units,
// 16 cols = 4 batches x 4 row-selects, each lane = one (unit,batch) pair).
// Round-6 diet: weights prescaled into exp2 domain (sigmoid rows x log2e,
// g rows x 2log2e) so nonlinearities are {exp2, add, rcp} with the negate
// folded into the v_exp VOP3 modifier; hand-unrolled x2 loop with static
// double-buffer pointers (no per-step addr math); v_cvt_pk_bf16_f32 for the
// h -> bf16 round (1 instr, RNE).
__global__ __launch_bounds__(256, 2) void lstm_mfma_kernel(
    const float* __restrict__ x,      // [B, T, 1]
    const float* __restrict__ W_ih,   // [4H, 1]
    const float* __restrict__ W_hh,   // [4H, H]
    const float* __restrict__ b_ih,   // [4H]
    const float* __restrict__ b_hh,   // [4H]
    const float* __restrict__ W_lin,  // [3, H]
    const float* __restrict__ b_lin,  // [3]
    float* __restrict__ out)          // [B, 3]
{
    const int tid  = threadIdx.x;
    const int lane = tid & 63;
    const int wv   = tid >> 6;       // wave 0..3
    const int col  = lane & 15;
    const int hi   = lane >> 4;      // k/row subgroup
    const int bq   = col & 3;        // batch serviced by this lane
    const int s    = col >> 2;       // C/D reg select: row = hi*4 + s
    const int b0   = blockIdx.x * BT;

    __shared__ float sx[BT][XS];
    __shared__ short hl[2][BT][HS];
    __shared__ float red[BT][3];

    for (int i = tid; i < 2 * BT * HS; i += 256) ((short*)hl)[i] = 0;

    // ---- stage all T for the 4 batches (coalesced float4) ----
    #pragma unroll
    for (int q = 0; q < 8; ++q) {
        const int idx = q * 256 + tid;
        const int row = idx >> 9;
        const int c4  = idx & 511;
        *(float4*)&sx[row][c4 * 4] =
            ((const float4*)(x + (size_t)(b0 + row) * T_LEN))[c4];
    }

    // ---- resident W_hh A-fragments (bf16), prescaled into exp2 domain ----
    const float scl[4] = {L2E, L2E, L2E2, L2E};   // i,f sigmoid; g tanh(2x); o sigmoid
    bf16x8 wf[4][2];
    #pragma unroll
    for (int g = 0; g < 4; ++g) {
        const int rowA = 64 * g + 16 * wv + col;
        #pragma unroll
        for (int kc = 0; kc < 2; ++kc) {
            const float* p = W_hh + rowA * HDIM + kc * 32 + hi * 8;
            bf16x8 f;
            #pragma unroll
            for (int j = 0; j < 8; ++j) f[j] = (short)f2bf(p[j] * scl[g]);
            wf[g][kc] = f;
        }
    }
    float wih1[4], bias1[4];
    #pragma unroll
    for (int g = 0; g < 4; ++g) {
        const int row = 64 * g + 16 * wv + hi * 4 + s;
        wih1[g]  = W_ih[row] * scl[g];
        bias1[g] = (b_ih[row] + b_hh[row]) * scl[g];
    }

    float cst = 0.f, hf = 0.f;
    const int sb0 = s & 1, sb1 = s >> 1;
    const int hwr = 16 * wv + hi * 4 + s;
    const int hi8 = hi * 8;

    // static double-buffer pointers: zero per-step address arithmetic
    const short* hrd0 = &hl[0][bq][0];
    const short* hrd1 = &hl[1][bq][0];
    short* hwp1 = &hl[1][bq][hwr];
    short* hwp0 = &hl[0][bq][hwr];
    const float* xp = &sx[bq][0];

    __syncthreads();   // covers hl zero-init + sx staging

#define STEP(HRD, HWP, XV) do {                                               \
    f32x4 a0, a1, a2, a3;                                                     \
    { const float tv = bias1[0] + wih1[0] * (XV); a0 = (f32x4){tv,tv,tv,tv};} \
    { const float tv = bias1[1] + wih1[1] * (XV); a1 = (f32x4){tv,tv,tv,tv};} \
    { const float tv = bias1[2] + wih1[2] * (XV); a2 = (f32x4){tv,tv,tv,tv};} \
    { const float tv = bias1[3] + wih1[3] * (XV); a3 = (f32x4){tv,tv,tv,tv};} \
    const bf16x8 hb0 = *(const bf16x8*)((HRD) + hi8);                         \
    const bf16x8 hb1 = *(const bf16x8*)((HRD) + 32 + hi8);                    \
    a0 = __builtin_amdgcn_mfma_f32_16x16x32_bf16(wf[0][0], hb0, a0, 0, 0, 0); \
    a1 = __builtin_amdgcn_mfma_f32_16x16x32_bf16(wf[1][0], hb0, a1, 0, 0, 0); \
    a2 = __builtin_amdgcn_mfma_f32_16x16x32_bf16(wf[2][0], hb0, a2, 0, 0, 0); \
    a3 = __builtin_amdgcn_mfma_f32_16x16x32_bf16(wf[3][0], hb0, a3, 0, 0, 0); \
    a0 = __builtin_amdgcn_mfma_f32_16x16x32_bf16(wf[0][1], hb1, a0, 0, 0, 0); \
    a1 = __builtin_amdgcn_mfma_f32_16x16x32_bf16(wf[1][1], hb1, a1, 0, 0, 0); \
    a2 = __builtin_amdgcn_mfma_f32_16x16x32_bf16(wf[2][1], hb1, a2, 0, 0, 0); \
    a3 = __builtin_amdgcn_mfma_f32_16x16x32_bf16(wf[3][1], hb1, a3, 0, 0, 0); \
    const float g0 = sb1 ? (sb0 ? a0[3] : a0[2]) : (sb0 ? a0[1] : a0[0]);     \
    const float g1 = sb1 ? (sb0 ? a1[3] : a1[2]) : (sb0 ? a1[1] : a1[0]);     \
    const float g2 = sb1 ? (sb0 ? a2[3] : a2[2]) : (sb0 ? a2[1] : a2[0]);     \
    const float g3 = sb1 ? (sb0 ? a3[3] : a3[2]) : (sb0 ? a3[1] : a3[0]);     \
    const float iv = rcp_f(1.0f + exp2_f(-g0));                               \
    const float fv = rcp_f(1.0f + exp2_f(-g1));                               \
    const float gv = 1.0f - 2.0f * rcp_f(exp2_f(g2) + 1.0f);                  \
    const float ov = rcp_f(1.0f + exp2_f(-g3));                               \
    cst = fv * cst + iv * gv;                                                 \
    const float th = 1.0f - 2.0f * rcp_f(exp2_f(L2E2 * cst) + 1.0f);          \
    hf = ov * th;                                                             \
    unsigned int rr;                                                          \
    asm("v_cvt_pk_bf16_f32 %0, %1, %1" : "=v"(rr) : "v"(hf));                 \
    *(HWP) = (short)rr;                                                       \
} while (0)

    for (int t = 0; t < T_LEN; t += 2) {
        const float2 xv2 = *(const float2*)(xp + t);   // one ds_read_b64
        STEP(hrd0, hwp1, xv2.x);
        __syncthreads();
        STEP(hrd1, hwp0, xv2.y);
        __syncthreads();
    }
#undef STEP

    // ---- epilogue: logits = W_lin @ h_T + b_lin, then log_softmax ----
    float p0 = W_lin[0 * HDIM + hwr] * hf;
    float p1 = W_lin[1 * HDIM + hwr] * hf;
    float p2 = W_lin[2 * HDIM + hwr] * hf;
    #pragma unroll
    for (int m = 4; m <= 32; m <<= 1) {
        p0 += __shfl_xor(p0, m);
        p1 += __shfl_xor(p1, m);
        p2 += __shfl_xor(p2, m);
    }
    if (tid < BT * 3) ((float*)red)[tid] = 0.f;
    __syncthreads();
    if (lane < 4) {
        atomicAdd(&red[lane][0], p0);
        atomicAdd(&red[lane][1], p1);
        atomicAdd(&red[lane][2], p2);
    }
    __syncthreads();
    if (tid < BT) {
        const float l0 = red[tid][0] + b_lin[0];
        const float l1 = red[tid][1] + b_lin[1];
        const float l2 = red[tid][2] + b_lin[2];
        const float m  = fmaxf(l0, fmaxf(l1, l2));
        const float sm = __expf(l0 - m) + __expf(l1 - m) + __expf(l2 - m);
        const float ls = __logf(sm);
        out[(b0 + tid) * 3 + 0] = l0 - m - ls;
        out[(b0 + tid) * 3 + 1] = l1 - m - ls;
        out[(b0 + tid) * 3 + 2] = l2 - m - ls;
    }
}

extern "C" void kernel_launch(void* const* d_in, const int* in_sizes, int n_in,
                              void* d_out, int out_size, void* d_ws, size_t ws_size,
                              hipStream_t stream) {
    const float* x     = (const float*)d_in[0];
    const float* W_ih  = (const float*)d_in[1];
    const float* W_hh  = (const float*)d_in[2];
    const float* b_ih  = (const float*)d_in[3];
    const float* b_hh  = (const float*)d_in[4];
    const float* W_lin = (const float*)d_in[5];
    const float* b_lin = (const float*)d_in[6];
    float* out = (float*)d_out;

    const int B = in_sizes[0] / T_LEN;   // 2048
    lstm_mfma_kernel<<<B / BT, 256, 0, stream>>>(x, W_ih, W_hh, b_ih, b_hh,
                                                 W_lin, b_lin, out);
}